// Round 1
// baseline (7102.751 us; speedup 1.0000x reference)
//
#include <hip/hip_runtime.h>
#include <hip/hip_bf16.h>
#include <math.h>

typedef __attribute__((ext_vector_type(8))) short bf16x8;
typedef __attribute__((ext_vector_type(4))) float f32x4;

#define VOCAB 50257
#define DIM   1024
#define HID   1024
#define TH3   3072
#define NL    2
#define NB    64
#define RCH   16

// ---------- fp32 -> bf16(hi) + bf16(lo) Dekker split, RNE both ----------
__device__ __forceinline__ unsigned short bf16_rne(float f) {
    unsigned int u = __float_as_uint(f);
    unsigned int r = u + 0x7FFFu + ((u >> 16) & 1u);
    return (unsigned short)(r >> 16);
}
__device__ __forceinline__ void split1(float f, unsigned short& h, unsigned short& l) {
    unsigned short hb = bf16_rne(f);
    float fh = __uint_as_float(((unsigned int)hb) << 16);
    h = hb;
    l = bf16_rne(f - fh);
}

// ---------- init: h = initial_hidden (+split), tok = start ----------
__global__ __launch_bounds__(256) void k_init(const float* __restrict__ h0,
                                              const int* __restrict__ start_tok,
                                              float* hbuf, unsigned short* hhi,
                                              unsigned short* hlo, int* tok) {
    int idx = blockIdx.x * 256 + threadIdx.x;
    if (idx < NL * NB * HID) {
        float v = h0[idx];
        hbuf[idx] = v;
        split1(v, hhi[idx], hlo[idx]);
    }
    if (idx < NB) tok[idx] = start_tok[0];
}

// ---------- x = embedding[tok], split ----------
__global__ __launch_bounds__(256) void k_prep_x(const float* __restrict__ emb,
                                                const int* __restrict__ tok,
                                                unsigned short* xhi, unsigned short* xlo) {
    int idx = blockIdx.x * 256 + threadIdx.x;      // NB*DIM = 65536
    int b = idx >> 10, k = idx & 1023;
    float v = emb[(size_t)tok[b] * DIM + k];
    split1(v, xhi[idx], xlo[idx]);
}

// ---------- shared MFMA tile: C[64 x 16-per-wave] += A[64,K] * W[n,K]^T ----------
__device__ __forceinline__ void mm_wave(const unsigned short* __restrict__ Ahi,
                                        const unsigned short* __restrict__ Alo,
                                        const float* __restrict__ W,
                                        int Ntot, int col, int k0, int klen,
                                        f32x4* acc) {
    const int lane = threadIdx.x & 63;
    const int colr = lane & 15;
    const int kg   = lane >> 4;
    const int colc = col < Ntot ? col : Ntot - 1;
    const float* wrow = W + (size_t)colc * 1024;
    for (int k = k0; k < k0 + klen; k += 32) {
        int ka = k + kg * 8;
        float4 b0 = *(const float4*)(wrow + ka);
        float4 b1 = *(const float4*)(wrow + ka + 4);
        float bv[8] = {b0.x, b0.y, b0.z, b0.w, b1.x, b1.y, b1.z, b1.w};
        bf16x8 bhi, blo;
#pragma unroll
        for (int j = 0; j < 8; ++j) {
            unsigned short h, l;
            split1(bv[j], h, l);
            bhi[j] = (short)h;
            blo[j] = (short)l;
        }
#pragma unroll
        for (int mt = 0; mt < 4; ++mt) {
            const bf16x8 ahi = *(const bf16x8*)(Ahi + (((mt * 16 + colr) << 10) + ka));
            const bf16x8 alo = *(const bf16x8*)(Alo + (((mt * 16 + colr) << 10) + ka));
            acc[mt] = __builtin_amdgcn_mfma_f32_16x16x32_bf16(ahi, bhi, acc[mt], 0, 0, 0);
            acc[mt] = __builtin_amdgcn_mfma_f32_16x16x32_bf16(alo, bhi, acc[mt], 0, 0, 0);
            acc[mt] = __builtin_amdgcn_mfma_f32_16x16x32_bf16(ahi, blo, acc[mt], 0, 0, 0);
        }
    }
}

// ---------- GRU matmuls: gpart[mat][kc][b][j] partial sums ----------
__global__ __launch_bounds__(256) void k_mm_gru(const unsigned short* __restrict__ Axhi,
                                                const unsigned short* __restrict__ Axlo,
                                                const unsigned short* __restrict__ Ahhi,
                                                const unsigned short* __restrict__ Ahlo,
                                                const float* __restrict__ Wih,
                                                const float* __restrict__ Whh,
                                                float* __restrict__ gpart) {
    const int mat = blockIdx.z;      // 0: x@Wih, 1: h@Whh
    const int kc  = blockIdx.y;      // K-chunk of 512
    const int wav = threadIdx.x >> 6;
    const int lane = threadIdx.x & 63;
    const int col = blockIdx.x * 64 + wav * 16 + (lane & 15);
    const unsigned short* Ahi = mat ? Ahhi : Axhi;
    const unsigned short* Alo = mat ? Ahlo : Axlo;
    const float* W = mat ? Whh : Wih;
    f32x4 acc[4] = {{0.f,0.f,0.f,0.f},{0.f,0.f,0.f,0.f},{0.f,0.f,0.f,0.f},{0.f,0.f,0.f,0.f}};
    mm_wave(Ahi, Alo, W, TH3, col, kc * 512, 512, acc);
    float* out = gpart + (size_t)(mat * 2 + kc) * NB * TH3;
    const int kg = lane >> 4;
#pragma unroll
    for (int mt = 0; mt < 4; ++mt)
#pragma unroll
        for (int r = 0; r < 4; ++r)
            out[(size_t)(mt * 16 + kg * 4 + r) * TH3 + col] = acc[mt][r];
}

// ---------- gate combine: h' = (1-z)n + z h ----------
__global__ __launch_bounds__(256) void k_gate(const float* __restrict__ gpart,
                                              const float* __restrict__ bih,
                                              const float* __restrict__ bhh,
                                              float* hbuf, unsigned short* hhi,
                                              unsigned short* hlo) {
    int idx = blockIdx.x * 256 + threadIdx.x;      // NB*HID
    int b = idx >> 10, i = idx & 1023;
    const float* g00 = gpart;                            // x@Wih kc0
    const float* g01 = gpart + (size_t)1 * NB * TH3;     // x@Wih kc1
    const float* g10 = gpart + (size_t)2 * NB * TH3;     // h@Whh kc0
    const float* g11 = gpart + (size_t)3 * NB * TH3;     // h@Whh kc1
    size_t o = (size_t)b * TH3;
    float ir = g00[o + i]            + g01[o + i]            + bih[i];
    float iz = g00[o + HID + i]      + g01[o + HID + i]      + bih[HID + i];
    float in = g00[o + 2 * HID + i]  + g01[o + 2 * HID + i]  + bih[2 * HID + i];
    float hr = g10[o + i]            + g11[o + i]            + bhh[i];
    float hz = g10[o + HID + i]      + g11[o + HID + i]      + bhh[HID + i];
    float hn = g10[o + 2 * HID + i]  + g11[o + 2 * HID + i]  + bhh[2 * HID + i];
    float r = 1.f / (1.f + expf(-(ir + hr)));
    float z = 1.f / (1.f + expf(-(iz + hz)));
    float n = tanhf(in + r * hn);
    float hold = hbuf[idx];
    float hnew = (1.f - z) * n + z * hold;
    hbuf[idx] = hnew;
    split1(hnew, hhi[idx], hlo[idx]);
}

// ---------- projection: logits[b][v] ----------
__global__ __launch_bounds__(256) void k_mm_proj(const unsigned short* __restrict__ Ahi,
                                                 const unsigned short* __restrict__ Alo,
                                                 const float* __restrict__ Wp,
                                                 const float* __restrict__ bp,
                                                 float* __restrict__ logits, int Vt) {
    const int wav = threadIdx.x >> 6;
    const int lane = threadIdx.x & 63;
    const int col = blockIdx.x * 64 + wav * 16 + (lane & 15);
    f32x4 acc[4] = {{0.f,0.f,0.f,0.f},{0.f,0.f,0.f,0.f},{0.f,0.f,0.f,0.f},{0.f,0.f,0.f,0.f}};
    mm_wave(Ahi, Alo, Wp, Vt, col, 0, 1024, acc);
    if (col < Vt) {
        float bv = bp[col];
        const int kg = lane >> 4;
#pragma unroll
        for (int mt = 0; mt < 4; ++mt)
#pragma unroll
            for (int r = 0; r < 4; ++r)
                logits[(size_t)(mt * 16 + kg * 4 + r) * Vt + col] = acc[mt][r] + bv;
    }
}

// ---------- per-(row,chunk) max/argmax/sumexp partials ----------
__global__ __launch_bounds__(256) void k_reduce(const float* __restrict__ logits,
                                                float* __restrict__ red, int Vt) {
    const int b = blockIdx.y, ch = blockIdx.x, tid = threadIdx.x;
    const int cs = (Vt + RCH - 1) / RCH;
    const int v0 = ch * cs;
    const int v1 = min(v0 + cs, Vt);
    const float* row = logits + (size_t)b * Vt;
    float m = -INFINITY; int mi = 0;
    for (int v = v0 + tid; v < v1; v += 256) {
        float x = row[v];
        if (x > m) { m = x; mi = v; }
    }
    __shared__ float sm[256]; __shared__ int si[256]; __shared__ float ss[256];
    sm[tid] = m; si[tid] = mi;
    __syncthreads();
    for (int s = 128; s > 0; s >>= 1) {
        if (tid < s) {
            float vo = sm[tid + s]; int io = si[tid + s];
            if (vo > sm[tid] || (vo == sm[tid] && io < si[tid])) { sm[tid] = vo; si[tid] = io; }
        }
        __syncthreads();
    }
    float mb = sm[0];
    float acc = 0.f;
    for (int v = v0 + tid; v < v1; v += 256) acc += expf(row[v] - mb);
    ss[tid] = acc;
    __syncthreads();
    for (int s = 128; s > 0; s >>= 1) {
        if (tid < s) ss[tid] += ss[tid + s];
        __syncthreads();
    }
    if (tid == 0)
        ((float4*)red)[b * RCH + ch] = make_float4(mb, ss[0], (float)si[0], 0.f);
}

// ---------- finalize: logp write + token select ----------
__global__ __launch_bounds__(256) void k_final(const float* __restrict__ logits,
                                               const float* __restrict__ red,
                                               float* __restrict__ out_logp,
                                               float* __restrict__ out_tok,
                                               int* __restrict__ toknext,
                                               int Vt, int Tt, int t) {
    const int b = blockIdx.y, tid = threadIdx.x;
    float mg = -INFINITY, ig = 0.f;
#pragma unroll
    for (int c = 0; c < RCH; ++c) {
        float4 p = ((const float4*)red)[b * RCH + c];
        if (p.x > mg) { mg = p.x; ig = p.z; }
        else if (p.x == mg && p.z < ig) { ig = p.z; }
    }
    float sg = 0.f;
#pragma unroll
    for (int c = 0; c < RCH; ++c) {
        float4 p = ((const float4*)red)[b * RCH + c];
        sg += p.y * expf(p.x - mg);
    }
    float lse = mg + logf(sg);
    const float* row = logits + (size_t)b * Vt;
    float* orow = out_logp + ((size_t)b * Tt + t) * Vt;
    const int base = blockIdx.x * 2048;
#pragma unroll
    for (int j = 0; j < 8; ++j) {
        int v = base + tid + j * 256;
        if (v < Vt) orow[v] = row[v] - lse;
    }
    if (blockIdx.x == 0 && tid == 0) {
        toknext[b] = (int)ig;
        out_tok[(size_t)b * Tt + t] = ig;
    }
}

extern "C" void kernel_launch(void* const* d_in, const int* in_sizes, int n_in,
                              void* d_out, int out_size, void* d_ws, size_t ws_size,
                              hipStream_t stream) {
    const float* emb    = (const float*)d_in[0];
    const float* w_ih   = (const float*)d_in[1];
    const float* w_hh   = (const float*)d_in[2];
    const float* b_ih   = (const float*)d_in[3];
    const float* b_hh   = (const float*)d_in[4];
    const float* w_proj = (const float*)d_in[5];
    const float* b_proj = (const float*)d_in[6];
    const float* h0     = (const float*)d_in[7];
    const int*   start  = (const int*)d_in[9];

    const int Vt = in_sizes[5] / HID;                 // 50257
    const int Tt = (int)((size_t)out_size / ((size_t)NB * (Vt + 1)));  // 32

    char* ws = (char*)d_ws;
    float* logits        = (float*)ws;  ws += (size_t)NB * Vt * 4;
    unsigned short* a0hi = (unsigned short*)ws;  ws += (size_t)NB * DIM * 2;
    unsigned short* a0lo = (unsigned short*)ws;  ws += (size_t)NB * DIM * 2;
    float* hbuf          = (float*)ws;  ws += (size_t)NL * NB * HID * 4;
    unsigned short* hhi  = (unsigned short*)ws;  ws += (size_t)NL * NB * HID * 2;
    unsigned short* hlo  = (unsigned short*)ws;  ws += (size_t)NL * NB * HID * 2;
    float* gpart         = (float*)ws;  ws += (size_t)4 * NB * TH3 * 4;
    float* red           = (float*)ws;  ws += (size_t)NB * RCH * 16;
    int* tok             = (int*)ws;    ws += 256;

    float* out_logp = (float*)d_out;
    float* out_tok  = (float*)d_out + (size_t)NB * Tt * Vt;

    k_init<<<(NL * NB * HID + 255) / 256, 256, 0, stream>>>(h0, start, hbuf, hhi, hlo, tok);

    for (int t = 0; t < Tt; ++t) {
        k_prep_x<<<NB * DIM / 256, 256, 0, stream>>>(emb, tok, a0hi, a0lo);
        for (int l = 0; l < NL; ++l) {
            const unsigned short* Axhi = (l == 0) ? a0hi : hhi;   // layer1 input = new h0
            const unsigned short* Axlo = (l == 0) ? a0lo : hlo;
            const unsigned short* Ahhi = hhi + (size_t)l * NB * HID;
            const unsigned short* Ahlo = hlo + (size_t)l * NB * HID;
            k_mm_gru<<<dim3(TH3 / 64, 2, 2), 256, 0, stream>>>(
                Axhi, Axlo, Ahhi, Ahlo,
                w_ih + (size_t)l * TH3 * DIM, w_hh + (size_t)l * TH3 * HID, gpart);
            k_gate<<<NB * HID / 256, 256, 0, stream>>>(
                gpart, b_ih + (size_t)l * TH3, b_hh + (size_t)l * TH3,
                hbuf + (size_t)l * NB * HID, hhi + (size_t)l * NB * HID,
                hlo + (size_t)l * NB * HID);
        }
        k_mm_proj<<<dim3((Vt + 63) / 64, 1, 1), 256, 0, stream>>>(
            hhi + (size_t)NB * HID, hlo + (size_t)NB * HID, w_proj, b_proj, logits, Vt);
        k_reduce<<<dim3(RCH, NB), 256, 0, stream>>>(logits, red, Vt);
        k_final<<<dim3((Vt + 2047) / 2048, NB), 256, 0, stream>>>(
            logits, red, out_logp, out_tok, tok, Vt, Tt, t);
    }
}

// Round 2
// 4527.913 us; speedup vs baseline: 1.5687x; 1.5687x over previous
//
#include <hip/hip_runtime.h>
#include <hip/hip_bf16.h>
#include <math.h>

typedef __attribute__((ext_vector_type(8))) short bf16x8;
typedef __attribute__((ext_vector_type(4))) float f32x4;

#define VOCAB 50257
#define VPAD  50304
#define NCT   (VPAD / 16)
#define DIM   1024
#define HID   1024
#define TH3   3072
#define NL    2
#define NB    64
#define RCH   16
#define KCS   8

// ---------- fp32 -> bf16(hi) + bf16(lo) Dekker split, RNE both ----------
__device__ __forceinline__ unsigned short bf16_rne(float f) {
    unsigned int u = __float_as_uint(f);
    unsigned int r = u + 0x7FFFu + ((u >> 16) & 1u);
    return (unsigned short)(r >> 16);
}
__device__ __forceinline__ void split1(float f, unsigned short& h, unsigned short& l) {
    unsigned short hb = bf16_rne(f);
    float fh = __uint_as_float(((unsigned int)hb) << 16);
    h = hb;
    l = bf16_rne(f - fh);
}

// tile layout: [rowtile16][kchunk32][lane64][j8]; lane = (k>>3 & 3)*16 + (row&15)
__device__ __forceinline__ size_t tpos(int r, int k) {
    int ct = r >> 4, colr = r & 15, kc = k >> 5, kg = (k >> 3) & 3, j = k & 7;
    return ((((size_t)ct * 32 + kc) * 64) + (kg * 16 + colr)) * 8 + j;
}

// ================= tiled path =================

// once-per-launch weight split into tiles
__global__ __launch_bounds__(256) void k_split_w(const float* __restrict__ W,
                                                 unsigned short* __restrict__ th,
                                                 unsigned short* __restrict__ tl,
                                                 int nrows, size_t total) {
    size_t idx = (size_t)blockIdx.x * 256 + threadIdx.x;
    if (idx >= total) return;
    int r = (int)(idx >> 10), k = (int)(idx & 1023);
    float v = (r < nrows) ? W[(size_t)r * 1024 + k] : 0.f;
    unsigned short h, l;
    split1(v, h, l);
    size_t p = tpos(r, k);
    th[p] = h;
    tl[p] = l;
}

__global__ __launch_bounds__(256) void k_init_t(const float* __restrict__ h0,
                                                const int* __restrict__ start_tok,
                                                float* hbuf, unsigned short* hth,
                                                unsigned short* htl, int* tok) {
    int idx = blockIdx.x * 256 + threadIdx.x;
    if (idx < NL * NB * HID) {
        float v = h0[idx];
        hbuf[idx] = v;
        int l = idx >> 16;                 // NB*HID = 65536
        int b = (idx >> 10) & 63, i = idx & 1023;
        unsigned short h, lo;
        split1(v, h, lo);
        size_t p = (size_t)l * 65536 + tpos(b, i);
        hth[p] = h;
        htl[p] = lo;
    }
    if (idx < NB) tok[idx] = start_tok[0];
}

__global__ __launch_bounds__(256) void k_prep_x_t(const float* __restrict__ emb,
                                                  const int* __restrict__ tok,
                                                  unsigned short* xth, unsigned short* xtl) {
    int idx = blockIdx.x * 256 + threadIdx.x;      // NB*DIM
    int b = idx >> 10, k = idx & 1023;
    float v = emb[(size_t)tok[b] * DIM + k];
    unsigned short h, l;
    split1(v, h, l);
    size_t p = tpos(b, k);
    xth[p] = h;
    xtl[p] = l;
}

// GRU matmuls (tiled): block = 128 cols x K-range of 128; both matrices
__global__ __launch_bounds__(256) void k_mm_gru_t(const unsigned short* __restrict__ Axh,
                                                  const unsigned short* __restrict__ Axl,
                                                  const unsigned short* __restrict__ Ahh,
                                                  const unsigned short* __restrict__ Ahl,
                                                  const unsigned short* __restrict__ Wihh,
                                                  const unsigned short* __restrict__ Wihl,
                                                  const unsigned short* __restrict__ Whhh,
                                                  const unsigned short* __restrict__ Whhl,
                                                  float* __restrict__ gpart) {
    const int wav = threadIdx.x >> 6, lane = threadIdx.x & 63;
    const int ct0 = blockIdx.x * 8 + wav * 2;
    const int kc0 = blockIdx.y * 4;
    const int colr = lane & 15, kg = lane >> 4;
    for (int m = 0; m < 2; ++m) {
        const bf16x8* A8h = (const bf16x8*)(m ? Ahh : Axh);
        const bf16x8* A8l = (const bf16x8*)(m ? Ahl : Axl);
        const bf16x8* B8h = (const bf16x8*)(m ? Whhh : Wihh);
        const bf16x8* B8l = (const bf16x8*)(m ? Whhl : Wihl);
        f32x4 acc[2][4];
#pragma unroll
        for (int nt = 0; nt < 2; ++nt)
#pragma unroll
            for (int mt = 0; mt < 4; ++mt)
                acc[nt][mt] = (f32x4){0.f, 0.f, 0.f, 0.f};
        for (int kc = kc0; kc < kc0 + 4; ++kc) {
            bf16x8 bh0 = B8h[((size_t)(ct0 + 0) * 32 + kc) * 64 + lane];
            bf16x8 bl0 = B8l[((size_t)(ct0 + 0) * 32 + kc) * 64 + lane];
            bf16x8 bh1 = B8h[((size_t)(ct0 + 1) * 32 + kc) * 64 + lane];
            bf16x8 bl1 = B8l[((size_t)(ct0 + 1) * 32 + kc) * 64 + lane];
#pragma unroll
            for (int mt = 0; mt < 4; ++mt) {
                bf16x8 ah = A8h[(mt * 32 + kc) * 64 + lane];
                bf16x8 al = A8l[(mt * 32 + kc) * 64 + lane];
                acc[0][mt] = __builtin_amdgcn_mfma_f32_16x16x32_bf16(ah, bh0, acc[0][mt], 0, 0, 0);
                acc[0][mt] = __builtin_amdgcn_mfma_f32_16x16x32_bf16(al, bh0, acc[0][mt], 0, 0, 0);
                acc[0][mt] = __builtin_amdgcn_mfma_f32_16x16x32_bf16(ah, bl0, acc[0][mt], 0, 0, 0);
                acc[1][mt] = __builtin_amdgcn_mfma_f32_16x16x32_bf16(ah, bh1, acc[1][mt], 0, 0, 0);
                acc[1][mt] = __builtin_amdgcn_mfma_f32_16x16x32_bf16(al, bh1, acc[1][mt], 0, 0, 0);
                acc[1][mt] = __builtin_amdgcn_mfma_f32_16x16x32_bf16(ah, bl1, acc[1][mt], 0, 0, 0);
            }
        }
        float* out = gpart + (size_t)(blockIdx.y * 2 + m) * 64 * TH3;
#pragma unroll
        for (int nt = 0; nt < 2; ++nt)
#pragma unroll
            for (int mt = 0; mt < 4; ++mt)
#pragma unroll
                for (int r = 0; r < 4; ++r) {
                    int col = (ct0 + nt) * 16 + colr;
                    int row = mt * 16 + kg * 4 + r;
                    out[(size_t)row * TH3 + col] = acc[nt][mt][r];
                }
    }
}

__global__ __launch_bounds__(256) void k_gate_t(const float* __restrict__ gpart,
                                                const float* __restrict__ bih,
                                                const float* __restrict__ bhh,
                                                float* hbuf, unsigned short* hth,
                                                unsigned short* htl) {
    int idx = blockIdx.x * 256 + threadIdx.x;      // NB*HID
    int b = idx >> 10, i = idx & 1023;
    float ir = bih[i], iz = bih[HID + i], in = bih[2 * HID + i];
    float hr = bhh[i], hz = bhh[HID + i], hn = bhh[2 * HID + i];
#pragma unroll
    for (int kc = 0; kc < KCS; ++kc) {
        const float* gi = gpart + ((size_t)(kc * 2 + 0) * 64 + b) * TH3;
        const float* gh = gpart + ((size_t)(kc * 2 + 1) * 64 + b) * TH3;
        ir += gi[i]; iz += gi[HID + i]; in += gi[2 * HID + i];
        hr += gh[i]; hz += gh[HID + i]; hn += gh[2 * HID + i];
    }
    float r = 1.f / (1.f + expf(-(ir + hr)));
    float z = 1.f / (1.f + expf(-(iz + hz)));
    float n = tanhf(in + r * hn);
    float hold = hbuf[idx];
    float hnew = (1.f - z) * n + z * hold;
    hbuf[idx] = hnew;
    unsigned short h, lo;
    split1(hnew, h, lo);
    size_t p = tpos(b, i);
    hth[p] = h;
    htl[p] = lo;
}

// projection (tiled): wave = 2 col-tiles (32 cols), full K
__global__ __launch_bounds__(256) void k_mm_proj_t(const unsigned short* __restrict__ Ah,
                                                   const unsigned short* __restrict__ Al,
                                                   const unsigned short* __restrict__ Bh,
                                                   const unsigned short* __restrict__ Bl,
                                                   const float* __restrict__ bp,
                                                   float* __restrict__ logits, int Vt) {
    const int wav = threadIdx.x >> 6, lane = threadIdx.x & 63;
    const int ct0 = blockIdx.x * 8 + wav * 2;
    const int colr = lane & 15, kg = lane >> 4;
    const bf16x8* A8h = (const bf16x8*)Ah;
    const bf16x8* A8l = (const bf16x8*)Al;
    const bf16x8* B8h = (const bf16x8*)Bh;
    const bf16x8* B8l = (const bf16x8*)Bl;
    f32x4 acc[2][4];
#pragma unroll
    for (int nt = 0; nt < 2; ++nt)
#pragma unroll
        for (int mt = 0; mt < 4; ++mt)
            acc[nt][mt] = (f32x4){0.f, 0.f, 0.f, 0.f};
    for (int kc = 0; kc < 32; ++kc) {
        bf16x8 bh0 = B8h[((size_t)(ct0 + 0) * 32 + kc) * 64 + lane];
        bf16x8 bl0 = B8l[((size_t)(ct0 + 0) * 32 + kc) * 64 + lane];
        bf16x8 bh1 = B8h[((size_t)(ct0 + 1) * 32 + kc) * 64 + lane];
        bf16x8 bl1 = B8l[((size_t)(ct0 + 1) * 32 + kc) * 64 + lane];
#pragma unroll
        for (int mt = 0; mt < 4; ++mt) {
            bf16x8 ah = A8h[(mt * 32 + kc) * 64 + lane];
            bf16x8 al = A8l[(mt * 32 + kc) * 64 + lane];
            acc[0][mt] = __builtin_amdgcn_mfma_f32_16x16x32_bf16(ah, bh0, acc[0][mt], 0, 0, 0);
            acc[0][mt] = __builtin_amdgcn_mfma_f32_16x16x32_bf16(al, bh0, acc[0][mt], 0, 0, 0);
            acc[0][mt] = __builtin_amdgcn_mfma_f32_16x16x32_bf16(ah, bl0, acc[0][mt], 0, 0, 0);
            acc[1][mt] = __builtin_amdgcn_mfma_f32_16x16x32_bf16(ah, bh1, acc[1][mt], 0, 0, 0);
            acc[1][mt] = __builtin_amdgcn_mfma_f32_16x16x32_bf16(al, bh1, acc[1][mt], 0, 0, 0);
            acc[1][mt] = __builtin_amdgcn_mfma_f32_16x16x32_bf16(ah, bl1, acc[1][mt], 0, 0, 0);
        }
    }
#pragma unroll
    for (int nt = 0; nt < 2; ++nt)
#pragma unroll
        for (int mt = 0; mt < 4; ++mt)
#pragma unroll
            for (int r = 0; r < 4; ++r) {
                int col = (ct0 + nt) * 16 + colr;
                int row = mt * 16 + kg * 4 + r;
                float bv = (col < Vt) ? bp[col] : 0.f;
                logits[(size_t)row * VPAD + col] = acc[nt][mt][r] + bv;
            }
}

// ================= fallback (round-1) path =================

__global__ __launch_bounds__(256) void k_init(const float* __restrict__ h0,
                                              const int* __restrict__ start_tok,
                                              float* hbuf, unsigned short* hhi,
                                              unsigned short* hlo, int* tok) {
    int idx = blockIdx.x * 256 + threadIdx.x;
    if (idx < NL * NB * HID) {
        float v = h0[idx];
        hbuf[idx] = v;
        split1(v, hhi[idx], hlo[idx]);
    }
    if (idx < NB) tok[idx] = start_tok[0];
}

__global__ __launch_bounds__(256) void k_prep_x(const float* __restrict__ emb,
                                                const int* __restrict__ tok,
                                                unsigned short* xhi, unsigned short* xlo) {
    int idx = blockIdx.x * 256 + threadIdx.x;
    int b = idx >> 10, k = idx & 1023;
    float v = emb[(size_t)tok[b] * DIM + k];
    split1(v, xhi[idx], xlo[idx]);
}

__device__ __forceinline__ void mm_wave(const unsigned short* __restrict__ Ahi,
                                        const unsigned short* __restrict__ Alo,
                                        const float* __restrict__ W,
                                        int Ntot, int col, int k0, int klen,
                                        f32x4* acc) {
    const int lane = threadIdx.x & 63;
    const int colr = lane & 15;
    const int kg   = lane >> 4;
    const int colc = col < Ntot ? col : Ntot - 1;
    const float* wrow = W + (size_t)colc * 1024;
    for (int k = k0; k < k0 + klen; k += 32) {
        int ka = k + kg * 8;
        float4 b0 = *(const float4*)(wrow + ka);
        float4 b1 = *(const float4*)(wrow + ka + 4);
        float bv[8] = {b0.x, b0.y, b0.z, b0.w, b1.x, b1.y, b1.z, b1.w};
        bf16x8 bhi, blo;
#pragma unroll
        for (int j = 0; j < 8; ++j) {
            unsigned short h, l;
            split1(bv[j], h, l);
            bhi[j] = (short)h;
            blo[j] = (short)l;
        }
#pragma unroll
        for (int mt = 0; mt < 4; ++mt) {
            const bf16x8 ahi = *(const bf16x8*)(Ahi + (((mt * 16 + colr) << 10) + ka));
            const bf16x8 alo = *(const bf16x8*)(Alo + (((mt * 16 + colr) << 10) + ka));
            acc[mt] = __builtin_amdgcn_mfma_f32_16x16x32_bf16(ahi, bhi, acc[mt], 0, 0, 0);
            acc[mt] = __builtin_amdgcn_mfma_f32_16x16x32_bf16(alo, bhi, acc[mt], 0, 0, 0);
            acc[mt] = __builtin_amdgcn_mfma_f32_16x16x32_bf16(ahi, blo, acc[mt], 0, 0, 0);
        }
    }
}

__global__ __launch_bounds__(256) void k_mm_gru(const unsigned short* __restrict__ Axhi,
                                                const unsigned short* __restrict__ Axlo,
                                                const unsigned short* __restrict__ Ahhi,
                                                const unsigned short* __restrict__ Ahlo,
                                                const float* __restrict__ Wih,
                                                const float* __restrict__ Whh,
                                                float* __restrict__ gpart) {
    const int mat = blockIdx.z;
    const int kc  = blockIdx.y;
    const int wav = threadIdx.x >> 6;
    const int lane = threadIdx.x & 63;
    const int col = blockIdx.x * 64 + wav * 16 + (lane & 15);
    const unsigned short* Ahi = mat ? Ahhi : Axhi;
    const unsigned short* Alo = mat ? Ahlo : Axlo;
    const float* W = mat ? Whh : Wih;
    f32x4 acc[4] = {{0.f,0.f,0.f,0.f},{0.f,0.f,0.f,0.f},{0.f,0.f,0.f,0.f},{0.f,0.f,0.f,0.f}};
    mm_wave(Ahi, Alo, W, TH3, col, kc * 512, 512, acc);
    float* out = gpart + (size_t)(mat * 2 + kc) * NB * TH3;
    const int kg = lane >> 4;
#pragma unroll
    for (int mt = 0; mt < 4; ++mt)
#pragma unroll
        for (int r = 0; r < 4; ++r)
            out[(size_t)(mt * 16 + kg * 4 + r) * TH3 + col] = acc[mt][r];
}

__global__ __launch_bounds__(256) void k_gate(const float* __restrict__ gpart,
                                              const float* __restrict__ bih,
                                              const float* __restrict__ bhh,
                                              float* hbuf, unsigned short* hhi,
                                              unsigned short* hlo) {
    int idx = blockIdx.x * 256 + threadIdx.x;
    int b = idx >> 10, i = idx & 1023;
    const float* g00 = gpart;
    const float* g01 = gpart + (size_t)1 * NB * TH3;
    const float* g10 = gpart + (size_t)2 * NB * TH3;
    const float* g11 = gpart + (size_t)3 * NB * TH3;
    size_t o = (size_t)b * TH3;
    float ir = g00[o + i]            + g01[o + i]            + bih[i];
    float iz = g00[o + HID + i]      + g01[o + HID + i]      + bih[HID + i];
    float in = g00[o + 2 * HID + i]  + g01[o + 2 * HID + i]  + bih[2 * HID + i];
    float hr = g10[o + i]            + g11[o + i]            + bhh[i];
    float hz = g10[o + HID + i]      + g11[o + HID + i]      + bhh[HID + i];
    float hn = g10[o + 2 * HID + i]  + g11[o + 2 * HID + i]  + bhh[2 * HID + i];
    float r = 1.f / (1.f + expf(-(ir + hr)));
    float z = 1.f / (1.f + expf(-(iz + hz)));
    float n = tanhf(in + r * hn);
    float hold = hbuf[idx];
    float hnew = (1.f - z) * n + z * hold;
    hbuf[idx] = hnew;
    split1(hnew, hhi[idx], hlo[idx]);
}

__global__ __launch_bounds__(256) void k_mm_proj(const unsigned short* __restrict__ Ahi,
                                                 const unsigned short* __restrict__ Alo,
                                                 const float* __restrict__ Wp,
                                                 const float* __restrict__ bp,
                                                 float* __restrict__ logits, int Vt) {
    const int wav = threadIdx.x >> 6;
    const int lane = threadIdx.x & 63;
    const int col = blockIdx.x * 64 + wav * 16 + (lane & 15);
    f32x4 acc[4] = {{0.f,0.f,0.f,0.f},{0.f,0.f,0.f,0.f},{0.f,0.f,0.f,0.f},{0.f,0.f,0.f,0.f}};
    mm_wave(Ahi, Alo, Wp, Vt, col, 0, 1024, acc);
    if (col < Vt) {
        float bv = bp[col];
        const int kg = lane >> 4;
#pragma unroll
        for (int mt = 0; mt < 4; ++mt)
#pragma unroll
            for (int r = 0; r < 4; ++r)
                logits[(size_t)(mt * 16 + kg * 4 + r) * Vt + col] = acc[mt][r] + bv;
    }
}

// ================= shared reduce / finalize =================

__global__ __launch_bounds__(256) void k_reduce(const float* __restrict__ logits,
                                                float* __restrict__ red, int Vt, int ldl) {
    const int b = blockIdx.y, ch = blockIdx.x, tid = threadIdx.x;
    const int cs = (Vt + RCH - 1) / RCH;
    const int v0 = ch * cs;
    const int v1 = min(v0 + cs, Vt);
    const float* row = logits + (size_t)b * ldl;
    float m = -INFINITY; int mi = 0;
    for (int v = v0 + tid; v < v1; v += 256) {
        float x = row[v];
        if (x > m) { m = x; mi = v; }
    }
    __shared__ float sm[256]; __shared__ int si[256]; __shared__ float ss[256];
    sm[tid] = m; si[tid] = mi;
    __syncthreads();
    for (int s = 128; s > 0; s >>= 1) {
        if (tid < s) {
            float vo = sm[tid + s]; int io = si[tid + s];
            if (vo > sm[tid] || (vo == sm[tid] && io < si[tid])) { sm[tid] = vo; si[tid] = io; }
        }
        __syncthreads();
    }
    float mb = sm[0];
    float acc = 0.f;
    for (int v = v0 + tid; v < v1; v += 256) acc += expf(row[v] - mb);
    ss[tid] = acc;
    __syncthreads();
    for (int s = 128; s > 0; s >>= 1) {
        if (tid < s) ss[tid] += ss[tid + s];
        __syncthreads();
    }
    if (tid == 0)
        ((float4*)red)[b * RCH + ch] = make_float4(mb, ss[0], (float)si[0], 0.f);
}

__global__ __launch_bounds__(256) void k_final(const float* __restrict__ logits,
                                               const float* __restrict__ red,
                                               float* __restrict__ out_logp,
                                               float* __restrict__ out_tok,
                                               int* __restrict__ toknext,
                                               int Vt, int ldl, int Tt, int t) {
    const int b = blockIdx.y, tid = threadIdx.x;
    float mg = -INFINITY, ig = 0.f;
#pragma unroll
    for (int c = 0; c < RCH; ++c) {
        float4 p = ((const float4*)red)[b * RCH + c];
        if (p.x > mg) { mg = p.x; ig = p.z; }
        else if (p.x == mg && p.z < ig) { ig = p.z; }
    }
    float sg = 0.f;
#pragma unroll
    for (int c = 0; c < RCH; ++c) {
        float4 p = ((const float4*)red)[b * RCH + c];
        sg += p.y * expf(p.x - mg);
    }
    float lse = mg + logf(sg);
    const float* row = logits + (size_t)b * ldl;
    float* orow = out_logp + ((size_t)b * Tt + t) * Vt;
    const int base = blockIdx.x * 2048;
#pragma unroll
    for (int j = 0; j < 8; ++j) {
        int v = base + tid + j * 256;
        if (v < Vt) orow[v] = row[v] - lse;
    }
    if (blockIdx.x == 0 && tid == 0) {
        toknext[b] = (int)ig;
        out_tok[(size_t)b * Tt + t] = ig;
    }
}

extern "C" void kernel_launch(void* const* d_in, const int* in_sizes, int n_in,
                              void* d_out, int out_size, void* d_ws, size_t ws_size,
                              hipStream_t stream) {
    const float* emb    = (const float*)d_in[0];
    const float* w_ih   = (const float*)d_in[1];
    const float* w_hh   = (const float*)d_in[2];
    const float* b_ih   = (const float*)d_in[3];
    const float* b_hh   = (const float*)d_in[4];
    const float* w_proj = (const float*)d_in[5];
    const float* b_proj = (const float*)d_in[6];
    const float* h0     = (const float*)d_in[7];
    const int*   start  = (const int*)d_in[9];

    const int Vt = in_sizes[5] / HID;                 // 50257
    const int Tt = (int)((size_t)out_size / ((size_t)NB * (Vt + 1)));  // 32

    float* out_logp = (float*)d_out;
    float* out_tok  = (float*)d_out + (size_t)NB * Tt * Vt;

    // tiled-path workspace layout
    const size_t SZ_BPROJ = (size_t)NCT * 32 * 64 * 8 * 2;        // 103,022,592 per half
    const size_t SZ_GRUW  = (size_t)(TH3 / 16) * 32 * 64 * 8 * 2; // 6,291,456 per half
    const size_t SZ_HT    = (size_t)65536 * 2;                    // per layer per half (bytes)

    char* ws = (char*)d_ws;
    size_t used = 0;
    auto alloc = [&](size_t bytes) {
        char* p = ws + used;
        used += (bytes + 255) & ~(size_t)255;
        return p;
    };
    float* logits        = (float*)alloc((size_t)NB * VPAD * 4);
    unsigned short* bpjh = (unsigned short*)alloc(SZ_BPROJ);
    unsigned short* bpjl = (unsigned short*)alloc(SZ_BPROJ);
    unsigned short* gwh[4]; unsigned short* gwl[4];   // [l*2+mat] mat0=ih mat1=hh
    for (int i = 0; i < 4; ++i) {
        gwh[i] = (unsigned short*)alloc(SZ_GRUW);
        gwl[i] = (unsigned short*)alloc(SZ_GRUW);
    }
    unsigned short* xth = (unsigned short*)alloc(SZ_HT);
    unsigned short* xtl = (unsigned short*)alloc(SZ_HT);
    unsigned short* hth = (unsigned short*)alloc(NL * SZ_HT);
    unsigned short* htl = (unsigned short*)alloc(NL * SZ_HT);
    float* hbuf          = (float*)alloc((size_t)NL * NB * HID * 4);
    float* gpart         = (float*)alloc((size_t)KCS * 2 * 64 * TH3 * 4);
    float* red           = (float*)alloc((size_t)NB * RCH * 16);
    int* tok             = (int*)alloc(256);

    if (ws_size >= used) {
        // ---- tiled path ----
        k_split_w<<<(int)(((size_t)VPAD * 1024 + 255) / 256), 256, 0, stream>>>(
            w_proj, bpjh, bpjl, Vt, (size_t)VPAD * 1024);
        for (int l = 0; l < NL; ++l) {
            k_split_w<<<(TH3 * 1024 / 256), 256, 0, stream>>>(
                w_ih + (size_t)l * TH3 * DIM, gwh[l * 2 + 0], gwl[l * 2 + 0], TH3, (size_t)TH3 * 1024);
            k_split_w<<<(TH3 * 1024 / 256), 256, 0, stream>>>(
                w_hh + (size_t)l * TH3 * HID, gwh[l * 2 + 1], gwl[l * 2 + 1], TH3, (size_t)TH3 * 1024);
        }
        k_init_t<<<(NL * NB * HID + 255) / 256, 256, 0, stream>>>(h0, start, hbuf, hth, htl, tok);

        for (int t = 0; t < Tt; ++t) {
            k_prep_x_t<<<NB * DIM / 256, 256, 0, stream>>>(emb, tok, xth, xtl);
            for (int l = 0; l < NL; ++l) {
                const unsigned short* Axh = (l == 0) ? xth : hth;
                const unsigned short* Axl = (l == 0) ? xtl : htl;
                const unsigned short* Ahh = hth + (size_t)l * 65536;
                const unsigned short* Ahl = htl + (size_t)l * 65536;
                k_mm_gru_t<<<dim3(TH3 / 128, KCS), 256, 0, stream>>>(
                    Axh, Axl, Ahh, Ahl,
                    gwh[l * 2 + 0], gwl[l * 2 + 0], gwh[l * 2 + 1], gwl[l * 2 + 1], gpart);
                k_gate_t<<<NB * HID / 256, 256, 0, stream>>>(
                    gpart, b_ih + (size_t)l * TH3, b_hh + (size_t)l * TH3,
                    hbuf + (size_t)l * NB * HID, hth + (size_t)l * 65536, htl + (size_t)l * 65536);
            }
            k_mm_proj_t<<<VPAD / 128, 256, 0, stream>>>(
                hth + 65536, htl + 65536, bpjh, bpjl, b_proj, logits, Vt);
            k_reduce<<<dim3(RCH, NB), 256, 0, stream>>>(logits, red, Vt, VPAD);
            k_final<<<dim3((Vt + 2047) / 2048, NB), 256, 0, stream>>>(
                logits, red, out_logp, out_tok, tok, Vt, VPAD, Tt, t);
        }
    } else {
        // ---- fallback (round-1) path ----
        char* w = (char*)d_ws;
        float* logitsF       = (float*)w;  w += (size_t)NB * Vt * 4;
        unsigned short* a0hi = (unsigned short*)w;  w += (size_t)NB * DIM * 2;
        unsigned short* a0lo = (unsigned short*)w;  w += (size_t)NB * DIM * 2;
        float* hbufF         = (float*)w;  w += (size_t)NL * NB * HID * 4;
        unsigned short* hhi  = (unsigned short*)w;  w += (size_t)NL * NB * HID * 2;
        unsigned short* hlo  = (unsigned short*)w;  w += (size_t)NL * NB * HID * 2;
        float* gpartF        = (float*)w;  w += (size_t)4 * NB * TH3 * 4;
        float* redF          = (float*)w;  w += (size_t)NB * RCH * 16;
        int* tokF            = (int*)w;    w += 256;

        k_init<<<(NL * NB * HID + 255) / 256, 256, 0, stream>>>(h0, start, hbufF, hhi, hlo, tokF);
        for (int t = 0; t < Tt; ++t) {
            k_prep_x<<<NB * DIM / 256, 256, 0, stream>>>(emb, tokF, a0hi, a0lo);
            for (int l = 0; l < NL; ++l) {
                const unsigned short* Axhi = (l == 0) ? a0hi : hhi;
                const unsigned short* Axlo = (l == 0) ? a0lo : hlo;
                const unsigned short* Ahhi = hhi + (size_t)l * NB * HID;
                const unsigned short* Ahlo = hlo + (size_t)l * NB * HID;
                k_mm_gru<<<dim3(TH3 / 64, 2, 2), 256, 0, stream>>>(
                    Axhi, Axlo, Ahhi, Ahlo,
                    w_ih + (size_t)l * TH3 * DIM, w_hh + (size_t)l * TH3 * HID, gpartF);
                k_gate<<<NB * HID / 256, 256, 0, stream>>>(
                    gpartF, b_ih + (size_t)l * TH3, b_hh + (size_t)l * TH3,
                    hbufF + (size_t)l * NB * HID, hhi + (size_t)l * NB * HID,
                    hlo + (size_t)l * NB * HID);
            }
            k_mm_proj<<<dim3((Vt + 63) / 64, 1, 1), 256, 0, stream>>>(
                hhi + (size_t)NB * HID, hlo + (size_t)NB * HID, w_proj, b_proj, logitsF, Vt);
            k_reduce<<<dim3(RCH, NB), 256, 0, stream>>>(logitsF, redF, Vt, Vt);
            k_final<<<dim3((Vt + 2047) / 2048, NB), 256, 0, stream>>>(
                logitsF, redF, out_logp, out_tok, tokF, Vt, Vt, Tt, t);
        }
    }
}

// Round 3
// 4121.049 us; speedup vs baseline: 1.7235x; 1.0987x over previous
//
#include <hip/hip_runtime.h>
#include <hip/hip_bf16.h>
#include <math.h>

typedef __attribute__((ext_vector_type(8))) short bf16x8;
typedef __attribute__((ext_vector_type(4))) float f32x4;

#define VOCAB 50257
#define VPAD  50304
#define NCT   (VPAD / 16)
#define DIM   1024
#define HID   1024
#define TH3   3072
#define NL    2
#define NB    64
#define RCH   16
#define GKC   16   // GRU K-chunks per matrix (K=64 each)

// ---------- fp32 -> bf16(hi) + bf16(lo) Dekker split, RNE both ----------
__device__ __forceinline__ unsigned short bf16_rne(float f) {
    unsigned int u = __float_as_uint(f);
    unsigned int r = u + 0x7FFFu + ((u >> 16) & 1u);
    return (unsigned short)(r >> 16);
}
__device__ __forceinline__ void split1(float f, unsigned short& h, unsigned short& l) {
    unsigned short hb = bf16_rne(f);
    float fh = __uint_as_float(((unsigned int)hb) << 16);
    h = hb;
    l = bf16_rne(f - fh);
}

// tile layout: [rowtile16][kchunk32][lane64][j8]; lane = (k>>3 & 3)*16 + (row&15)
__device__ __forceinline__ size_t tpos(int r, int k) {
    int ct = r >> 4, colr = r & 15, kc = k >> 5, kg = (k >> 3) & 3, j = k & 7;
    return ((((size_t)ct * 32 + kc) * 64) + (kg * 16 + colr)) * 8 + j;
}

// ================= tiled path =================

__global__ __launch_bounds__(256) void k_split_w(const float* __restrict__ W,
                                                 unsigned short* __restrict__ th,
                                                 unsigned short* __restrict__ tl,
                                                 int nrows, size_t total) {
    size_t idx = (size_t)blockIdx.x * 256 + threadIdx.x;
    if (idx >= total) return;
    int r = (int)(idx >> 10), k = (int)(idx & 1023);
    float v = (r < nrows) ? W[(size_t)r * 1024 + k] : 0.f;
    unsigned short h, l;
    split1(v, h, l);
    size_t p = tpos(r, k);
    th[p] = h;
    tl[p] = l;
}

__global__ __launch_bounds__(256) void k_init_t(const float* __restrict__ h0,
                                                const int* __restrict__ start_tok,
                                                float* hbuf, unsigned short* hth,
                                                unsigned short* htl, int* tok) {
    int idx = blockIdx.x * 256 + threadIdx.x;
    if (idx < NL * NB * HID) {
        float v = h0[idx];
        hbuf[idx] = v;
        int l = idx >> 16;
        int b = (idx >> 10) & 63, i = idx & 1023;
        unsigned short h, lo;
        split1(v, h, lo);
        size_t p = (size_t)l * 65536 + tpos(b, i);
        hth[p] = h;
        htl[p] = lo;
    }
    if (idx < NB) tok[idx] = start_tok[0];
}

__global__ __launch_bounds__(256) void k_prep_x_t(const float* __restrict__ emb,
                                                  const int* __restrict__ tok,
                                                  unsigned short* xth, unsigned short* xtl) {
    int idx = blockIdx.x * 256 + threadIdx.x;
    int b = idx >> 10, k = idx & 1023;
    float v = emb[(size_t)tok[b] * DIM + k];
    unsigned short h, l;
    split1(v, h, l);
    size_t p = tpos(b, k);
    xth[p] = h;
    xtl[p] = l;
}

// GRU matmul (tiled): z = matrix, y = K-chunk of 64, x = 128-col group
__global__ __launch_bounds__(256) void k_mm_gru_t(const unsigned short* __restrict__ Axh,
                                                  const unsigned short* __restrict__ Axl,
                                                  const unsigned short* __restrict__ Ahh,
                                                  const unsigned short* __restrict__ Ahl,
                                                  const unsigned short* __restrict__ Wihh,
                                                  const unsigned short* __restrict__ Wihl,
                                                  const unsigned short* __restrict__ Whhh,
                                                  const unsigned short* __restrict__ Whhl,
                                                  float* __restrict__ gpart) {
    const int wav = threadIdx.x >> 6, lane = threadIdx.x & 63;
    const int ct0 = blockIdx.x * 8 + wav * 2;
    const int kc0 = blockIdx.y * 2;
    const int m = blockIdx.z;
    const int colr = lane & 15, kg = lane >> 4;
    const bf16x8* A8h = (const bf16x8*)(m ? Ahh : Axh);
    const bf16x8* A8l = (const bf16x8*)(m ? Ahl : Axl);
    const bf16x8* B8h = (const bf16x8*)(m ? Whhh : Wihh);
    const bf16x8* B8l = (const bf16x8*)(m ? Whhl : Wihl);
    f32x4 acc[2][4];
#pragma unroll
    for (int nt = 0; nt < 2; ++nt)
#pragma unroll
        for (int mt = 0; mt < 4; ++mt)
            acc[nt][mt] = (f32x4){0.f, 0.f, 0.f, 0.f};
#pragma unroll
    for (int i = 0; i < 2; ++i) {
        int kc = kc0 + i;
        bf16x8 bh0 = B8h[((size_t)(ct0 + 0) * 32 + kc) * 64 + lane];
        bf16x8 bl0 = B8l[((size_t)(ct0 + 0) * 32 + kc) * 64 + lane];
        bf16x8 bh1 = B8h[((size_t)(ct0 + 1) * 32 + kc) * 64 + lane];
        bf16x8 bl1 = B8l[((size_t)(ct0 + 1) * 32 + kc) * 64 + lane];
#pragma unroll
        for (int mt = 0; mt < 4; ++mt) {
            bf16x8 ah = A8h[(mt * 32 + kc) * 64 + lane];
            bf16x8 al = A8l[(mt * 32 + kc) * 64 + lane];
            acc[0][mt] = __builtin_amdgcn_mfma_f32_16x16x32_bf16(ah, bh0, acc[0][mt], 0, 0, 0);
            acc[0][mt] = __builtin_amdgcn_mfma_f32_16x16x32_bf16(al, bh0, acc[0][mt], 0, 0, 0);
            acc[0][mt] = __builtin_amdgcn_mfma_f32_16x16x32_bf16(ah, bl0, acc[0][mt], 0, 0, 0);
            acc[1][mt] = __builtin_amdgcn_mfma_f32_16x16x32_bf16(ah, bh1, acc[1][mt], 0, 0, 0);
            acc[1][mt] = __builtin_amdgcn_mfma_f32_16x16x32_bf16(al, bh1, acc[1][mt], 0, 0, 0);
            acc[1][mt] = __builtin_amdgcn_mfma_f32_16x16x32_bf16(ah, bl1, acc[1][mt], 0, 0, 0);
        }
    }
    float* out = gpart + (size_t)(m * GKC + blockIdx.y) * 64 * TH3;
#pragma unroll
    for (int nt = 0; nt < 2; ++nt)
#pragma unroll
        for (int mt = 0; mt < 4; ++mt)
#pragma unroll
            for (int r = 0; r < 4; ++r) {
                int col = (ct0 + nt) * 16 + colr;
                int row = mt * 16 + kg * 4 + r;
                out[(size_t)row * TH3 + col] = acc[nt][mt][r];
            }
}

__global__ __launch_bounds__(256) void k_gate_t(const float* __restrict__ gpart,
                                                const float* __restrict__ bih,
                                                const float* __restrict__ bhh,
                                                float* hbuf, unsigned short* hth,
                                                unsigned short* htl) {
    int idx = blockIdx.x * 256 + threadIdx.x;
    int b = idx >> 10, i = idx & 1023;
    float ir = bih[i], iz = bih[HID + i], in = bih[2 * HID + i];
    float hr = bhh[i], hz = bhh[HID + i], hn = bhh[2 * HID + i];
#pragma unroll
    for (int kc = 0; kc < GKC; ++kc) {
        const float* gi = gpart + ((size_t)kc * 64 + b) * TH3;
        const float* gh = gpart + ((size_t)(GKC + kc) * 64 + b) * TH3;
        ir += gi[i]; iz += gi[HID + i]; in += gi[2 * HID + i];
        hr += gh[i]; hz += gh[HID + i]; hn += gh[2 * HID + i];
    }
    float r = 1.f / (1.f + expf(-(ir + hr)));
    float z = 1.f / (1.f + expf(-(iz + hz)));
    float n = tanhf(in + r * hn);
    float hold = hbuf[idx];
    float hnew = (1.f - z) * n + z * hold;
    hbuf[idx] = hnew;
    unsigned short h, lo;
    split1(hnew, h, lo);
    size_t p = tpos(b, i);
    hth[p] = h;
    htl[p] = lo;
}

// projection (tiled, K-split 2): writes raw partials
__global__ __launch_bounds__(256) void k_mm_proj_t(const unsigned short* __restrict__ Ah,
                                                   const unsigned short* __restrict__ Al,
                                                   const unsigned short* __restrict__ Bh,
                                                   const unsigned short* __restrict__ Bl,
                                                   float* __restrict__ part) {
    const int wav = threadIdx.x >> 6, lane = threadIdx.x & 63;
    const int ct0 = blockIdx.x * 8 + wav * 2;
    const int kc0 = blockIdx.y * 16;
    const int colr = lane & 15, kg = lane >> 4;
    const bf16x8* A8h = (const bf16x8*)Ah;
    const bf16x8* A8l = (const bf16x8*)Al;
    const bf16x8* B8h = (const bf16x8*)Bh;
    const bf16x8* B8l = (const bf16x8*)Bl;
    f32x4 acc[2][4];
#pragma unroll
    for (int nt = 0; nt < 2; ++nt)
#pragma unroll
        for (int mt = 0; mt < 4; ++mt)
            acc[nt][mt] = (f32x4){0.f, 0.f, 0.f, 0.f};
#pragma unroll 2
    for (int kc = kc0; kc < kc0 + 16; ++kc) {
        bf16x8 bh0 = B8h[((size_t)(ct0 + 0) * 32 + kc) * 64 + lane];
        bf16x8 bl0 = B8l[((size_t)(ct0 + 0) * 32 + kc) * 64 + lane];
        bf16x8 bh1 = B8h[((size_t)(ct0 + 1) * 32 + kc) * 64 + lane];
        bf16x8 bl1 = B8l[((size_t)(ct0 + 1) * 32 + kc) * 64 + lane];
#pragma unroll
        for (int mt = 0; mt < 4; ++mt) {
            bf16x8 ah = A8h[(mt * 32 + kc) * 64 + lane];
            bf16x8 al = A8l[(mt * 32 + kc) * 64 + lane];
            acc[0][mt] = __builtin_amdgcn_mfma_f32_16x16x32_bf16(ah, bh0, acc[0][mt], 0, 0, 0);
            acc[0][mt] = __builtin_amdgcn_mfma_f32_16x16x32_bf16(al, bh0, acc[0][mt], 0, 0, 0);
            acc[0][mt] = __builtin_amdgcn_mfma_f32_16x16x32_bf16(ah, bl0, acc[0][mt], 0, 0, 0);
            acc[1][mt] = __builtin_amdgcn_mfma_f32_16x16x32_bf16(ah, bh1, acc[1][mt], 0, 0, 0);
            acc[1][mt] = __builtin_amdgcn_mfma_f32_16x16x32_bf16(al, bh1, acc[1][mt], 0, 0, 0);
            acc[1][mt] = __builtin_amdgcn_mfma_f32_16x16x32_bf16(ah, bl1, acc[1][mt], 0, 0, 0);
        }
    }
    float* out = part + (size_t)blockIdx.y * NB * VPAD;
#pragma unroll
    for (int nt = 0; nt < 2; ++nt)
#pragma unroll
        for (int mt = 0; mt < 4; ++mt)
#pragma unroll
            for (int r = 0; r < 4; ++r) {
                int col = (ct0 + nt) * 16 + colr;
                int row = mt * 16 + kg * 4 + r;
                out[(size_t)row * VPAD + col] = acc[nt][mt][r];
            }
}

// reduce: combine partials + bias -> logits row; per-chunk max/argmax/sumexp
__global__ __launch_bounds__(256) void k_reduce2(const float* __restrict__ part,
                                                 const float* __restrict__ bp,
                                                 float* __restrict__ logits,
                                                 float* __restrict__ red, int Vt) {
    const int b = blockIdx.y, ch = blockIdx.x, tid = threadIdx.x;
    const int cs = (Vt + RCH - 1) / RCH;
    const int v0 = ch * cs;
    const int v1 = min(v0 + cs, Vt);
    const float* p0 = part + (size_t)b * VPAD;
    const float* p1 = part + (size_t)(NB + b) * VPAD;
    float* lrow = logits + (size_t)b * VPAD;
    float m = -INFINITY; int mi = 0;
    for (int v = v0 + tid; v < v1; v += 256) {
        float x = p0[v] + p1[v] + bp[v];
        lrow[v] = x;
        if (x > m) { m = x; mi = v; }
    }
    __shared__ float sm[256]; __shared__ int si[256]; __shared__ float ss[256];
    sm[tid] = m; si[tid] = mi;
    __syncthreads();
    for (int s = 128; s > 0; s >>= 1) {
        if (tid < s) {
            float vo = sm[tid + s]; int io = si[tid + s];
            if (vo > sm[tid] || (vo == sm[tid] && io < si[tid])) { sm[tid] = vo; si[tid] = io; }
        }
        __syncthreads();
    }
    float mb = sm[0];
    float acc = 0.f;
    for (int v = v0 + tid; v < v1; v += 256) acc += expf(lrow[v] - mb);
    ss[tid] = acc;
    __syncthreads();
    for (int s = 128; s > 0; s >>= 1) {
        if (tid < s) ss[tid] += ss[tid + s];
        __syncthreads();
    }
    if (tid == 0)
        ((float4*)red)[b * RCH + ch] = make_float4(mb, ss[0], (float)si[0], 0.f);
}

__global__ __launch_bounds__(256) void k_final(const float* __restrict__ logits,
                                               const float* __restrict__ red,
                                               float* __restrict__ out_logp,
                                               float* __restrict__ out_tok,
                                               int* __restrict__ toknext,
                                               int Vt, int ldl, int Tt, int t) {
    const int b = blockIdx.y, tid = threadIdx.x;
    float mg = -INFINITY, ig = 0.f;
#pragma unroll
    for (int c = 0; c < RCH; ++c) {
        float4 p = ((const float4*)red)[b * RCH + c];
        if (p.x > mg) { mg = p.x; ig = p.z; }
        else if (p.x == mg && p.z < ig) { ig = p.z; }
    }
    float sg = 0.f;
#pragma unroll
    for (int c = 0; c < RCH; ++c) {
        float4 p = ((const float4*)red)[b * RCH + c];
        sg += p.y * expf(p.x - mg);
    }
    float lse = mg + logf(sg);
    const float* row = logits + (size_t)b * ldl;
    float* orow = out_logp + ((size_t)b * Tt + t) * Vt;
    const int base = blockIdx.x * 2048;
#pragma unroll
    for (int j = 0; j < 8; ++j) {
        int v = base + tid + j * 256;
        if (v < Vt) orow[v] = row[v] - lse;
    }
    if (blockIdx.x == 0 && tid == 0) {
        toknext[b] = (int)ig;
        out_tok[(size_t)b * Tt + t] = ig;
    }
}

// ================= fallback (round-1) path =================

__global__ __launch_bounds__(256) void k_init(const float* __restrict__ h0,
                                              const int* __restrict__ start_tok,
                                              float* hbuf, unsigned short* hhi,
                                              unsigned short* hlo, int* tok) {
    int idx = blockIdx.x * 256 + threadIdx.x;
    if (idx < NL * NB * HID) {
        float v = h0[idx];
        hbuf[idx] = v;
        split1(v, hhi[idx], hlo[idx]);
    }
    if (idx < NB) tok[idx] = start_tok[0];
}

__global__ __launch_bounds__(256) void k_prep_x(const float* __restrict__ emb,
                                                const int* __restrict__ tok,
                                                unsigned short* xhi, unsigned short* xlo) {
    int idx = blockIdx.x * 256 + threadIdx.x;
    int b = idx >> 10, k = idx & 1023;
    float v = emb[(size_t)tok[b] * DIM + k];
    split1(v, xhi[idx], xlo[idx]);
}

__device__ __forceinline__ void mm_wave(const unsigned short* __restrict__ Ahi,
                                        const unsigned short* __restrict__ Alo,
                                        const float* __restrict__ W,
                                        int Ntot, int col, int k0, int klen,
                                        f32x4* acc) {
    const int lane = threadIdx.x & 63;
    const int colr = lane & 15;
    const int kg   = lane >> 4;
    const int colc = col < Ntot ? col : Ntot - 1;
    const float* wrow = W + (size_t)colc * 1024;
    for (int k = k0; k < k0 + klen; k += 32) {
        int ka = k + kg * 8;
        float4 b0 = *(const float4*)(wrow + ka);
        float4 b1 = *(const float4*)(wrow + ka + 4);
        float bv[8] = {b0.x, b0.y, b0.z, b0.w, b1.x, b1.y, b1.z, b1.w};
        bf16x8 bhi, blo;
#pragma unroll
        for (int j = 0; j < 8; ++j) {
            unsigned short h, l;
            split1(bv[j], h, l);
            bhi[j] = (short)h;
            blo[j] = (short)l;
        }
#pragma unroll
        for (int mt = 0; mt < 4; ++mt) {
            const bf16x8 ahi = *(const bf16x8*)(Ahi + (((mt * 16 + colr) << 10) + ka));
            const bf16x8 alo = *(const bf16x8*)(Alo + (((mt * 16 + colr) << 10) + ka));
            acc[mt] = __builtin_amdgcn_mfma_f32_16x16x32_bf16(ahi, bhi, acc[mt], 0, 0, 0);
            acc[mt] = __builtin_amdgcn_mfma_f32_16x16x32_bf16(alo, bhi, acc[mt], 0, 0, 0);
            acc[mt] = __builtin_amdgcn_mfma_f32_16x16x32_bf16(ahi, blo, acc[mt], 0, 0, 0);
        }
    }
}

__global__ __launch_bounds__(256) void k_mm_gru(const unsigned short* __restrict__ Axhi,
                                                const unsigned short* __restrict__ Axlo,
                                                const unsigned short* __restrict__ Ahhi,
                                                const unsigned short* __restrict__ Ahlo,
                                                const float* __restrict__ Wih,
                                                const float* __restrict__ Whh,
                                                float* __restrict__ gpart) {
    const int mat = blockIdx.z;
    const int kc  = blockIdx.y;
    const int wav = threadIdx.x >> 6;
    const int lane = threadIdx.x & 63;
    const int col = blockIdx.x * 64 + wav * 16 + (lane & 15);
    const unsigned short* Ahi = mat ? Ahhi : Axhi;
    const unsigned short* Alo = mat ? Ahlo : Axlo;
    const float* W = mat ? Whh : Wih;
    f32x4 acc[4] = {{0.f,0.f,0.f,0.f},{0.f,0.f,0.f,0.f},{0.f,0.f,0.f,0.f},{0.f,0.f,0.f,0.f}};
    mm_wave(Ahi, Alo, W, TH3, col, kc * 512, 512, acc);
    float* out = gpart + (size_t)(mat * 2 + kc) * NB * TH3;
    const int kg = lane >> 4;
#pragma unroll
    for (int mt = 0; mt < 4; ++mt)
#pragma unroll
        for (int r = 0; r < 4; ++r)
            out[(size_t)(mt * 16 + kg * 4 + r) * TH3 + col] = acc[mt][r];
}

__global__ __launch_bounds__(256) void k_gate(const float* __restrict__ gpart,
                                              const float* __restrict__ bih,
                                              const float* __restrict__ bhh,
                                              float* hbuf, unsigned short* hhi,
                                              unsigned short* hlo) {
    int idx = blockIdx.x * 256 + threadIdx.x;
    int b = idx >> 10, i = idx & 1023;
    const float* g00 = gpart;
    const float* g01 = gpart + (size_t)1 * NB * TH3;
    const float* g10 = gpart + (size_t)2 * NB * TH3;
    const float* g11 = gpart + (size_t)3 * NB * TH3;
    size_t o = (size_t)b * TH3;
    float ir = g00[o + i]            + g01[o + i]            + bih[i];
    float iz = g00[o + HID + i]      + g01[o + HID + i]      + bih[HID + i];
    float in = g00[o + 2 * HID + i]  + g01[o + 2 * HID + i]  + bih[2 * HID + i];
    float hr = g10[o + i]            + g11[o + i]            + bhh[i];
    float hz = g10[o + HID + i]      + g11[o + HID + i]      + bhh[HID + i];
    float hn = g10[o + 2 * HID + i]  + g11[o + 2 * HID + i]  + bhh[2 * HID + i];
    float r = 1.f / (1.f + expf(-(ir + hr)));
    float z = 1.f / (1.f + expf(-(iz + hz)));
    float n = tanhf(in + r * hn);
    float hold = hbuf[idx];
    float hnew = (1.f - z) * n + z * hold;
    hbuf[idx] = hnew;
    split1(hnew, hhi[idx], hlo[idx]);
}

__global__ __launch_bounds__(256) void k_mm_proj(const unsigned short* __restrict__ Ahi,
                                                 const unsigned short* __restrict__ Alo,
                                                 const float* __restrict__ Wp,
                                                 const float* __restrict__ bp,
                                                 float* __restrict__ logits, int Vt) {
    const int wav = threadIdx.x >> 6;
    const int lane = threadIdx.x & 63;
    const int col = blockIdx.x * 64 + wav * 16 + (lane & 15);
    f32x4 acc[4] = {{0.f,0.f,0.f,0.f},{0.f,0.f,0.f,0.f},{0.f,0.f,0.f,0.f},{0.f,0.f,0.f,0.f}};
    mm_wave(Ahi, Alo, Wp, Vt, col, 0, 1024, acc);
    if (col < Vt) {
        float bv = bp[col];
        const int kg = lane >> 4;
#pragma unroll
        for (int mt = 0; mt < 4; ++mt)
#pragma unroll
            for (int r = 0; r < 4; ++r)
                logits[(size_t)(mt * 16 + kg * 4 + r) * Vt + col] = acc[mt][r] + bv;
    }
}

__global__ __launch_bounds__(256) void k_reduce(const float* __restrict__ logits,
                                                float* __restrict__ red, int Vt, int ldl) {
    const int b = blockIdx.y, ch = blockIdx.x, tid = threadIdx.x;
    const int cs = (Vt + RCH - 1) / RCH;
    const int v0 = ch * cs;
    const int v1 = min(v0 + cs, Vt);
    const float* row = logits + (size_t)b * ldl;
    float m = -INFINITY; int mi = 0;
    for (int v = v0 + tid; v < v1; v += 256) {
        float x = row[v];
        if (x > m) { m = x; mi = v; }
    }
    __shared__ float sm[256]; __shared__ int si[256]; __shared__ float ss[256];
    sm[tid] = m; si[tid] = mi;
    __syncthreads();
    for (int s = 128; s > 0; s >>= 1) {
        if (tid < s) {
            float vo = sm[tid + s]; int io = si[tid + s];
            if (vo > sm[tid] || (vo == sm[tid] && io < si[tid])) { sm[tid] = vo; si[tid] = io; }
        }
        __syncthreads();
    }
    float mb = sm[0];
    float acc = 0.f;
    for (int v = v0 + tid; v < v1; v += 256) acc += expf(row[v] - mb);
    ss[tid] = acc;
    __syncthreads();
    for (int s = 128; s > 0; s >>= 1) {
        if (tid < s) ss[tid] += ss[tid + s];
        __syncthreads();
    }
    if (tid == 0)
        ((float4*)red)[b * RCH + ch] = make_float4(mb, ss[0], (float)si[0], 0.f);
}

extern "C" void kernel_launch(void* const* d_in, const int* in_sizes, int n_in,
                              void* d_out, int out_size, void* d_ws, size_t ws_size,
                              hipStream_t stream) {
    const float* emb    = (const float*)d_in[0];
    const float* w_ih   = (const float*)d_in[1];
    const float* w_hh   = (const float*)d_in[2];
    const float* b_ih   = (const float*)d_in[3];
    const float* b_hh   = (const float*)d_in[4];
    const float* w_proj = (const float*)d_in[5];
    const float* b_proj = (const float*)d_in[6];
    const float* h0     = (const float*)d_in[7];
    const int*   start  = (const int*)d_in[9];

    const int Vt = in_sizes[5] / HID;                 // 50257
    const int Tt = (int)((size_t)out_size / ((size_t)NB * (Vt + 1)));  // 32

    float* out_logp = (float*)d_out;
    float* out_tok  = (float*)d_out + (size_t)NB * Tt * Vt;

    const size_t SZ_BPROJ = (size_t)NCT * 32 * 64 * 8 * 2;
    const size_t SZ_GRUW  = (size_t)(TH3 / 16) * 32 * 64 * 8 * 2;
    const size_t SZ_HT    = (size_t)65536 * 2;
    // gpart doubles as proj partial buffer: max(32 gru slabs, 2 proj slabs)
    const size_t SZ_GPART = (size_t)2 * GKC * 64 * TH3 * 4 > (size_t)2 * NB * VPAD * 4
                          ? (size_t)2 * GKC * 64 * TH3 * 4 : (size_t)2 * NB * VPAD * 4;

    char* ws = (char*)d_ws;
    size_t used = 0;
    auto alloc = [&](size_t bytes) {
        char* p = ws + used;
        used += (bytes + 255) & ~(size_t)255;
        return p;
    };
    float* logits        = (float*)alloc((size_t)NB * VPAD * 4);
    unsigned short* bpjh = (unsigned short*)alloc(SZ_BPROJ);
    unsigned short* bpjl = (unsigned short*)alloc(SZ_BPROJ);
    unsigned short* gwh[4]; unsigned short* gwl[4];
    for (int i = 0; i < 4; ++i) {
        gwh[i] = (unsigned short*)alloc(SZ_GRUW);
        gwl[i] = (unsigned short*)alloc(SZ_GRUW);
    }
    unsigned short* xth = (unsigned short*)alloc(SZ_HT);
    unsigned short* xtl = (unsigned short*)alloc(SZ_HT);
    unsigned short* hth = (unsigned short*)alloc(NL * SZ_HT);
    unsigned short* htl = (unsigned short*)alloc(NL * SZ_HT);
    float* hbuf          = (float*)alloc((size_t)NL * NB * HID * 4);
    float* gpart         = (float*)alloc(SZ_GPART);
    float* red           = (float*)alloc((size_t)NB * RCH * 16);
    int* tok             = (int*)alloc(256);

    if (ws_size >= used) {
        // ---- tiled path ----
        k_split_w<<<(int)(((size_t)VPAD * 1024 + 255) / 256), 256, 0, stream>>>(
            w_proj, bpjh, bpjl, Vt, (size_t)VPAD * 1024);
        for (int l = 0; l < NL; ++l) {
            k_split_w<<<(TH3 * 1024 / 256), 256, 0, stream>>>(
                w_ih + (size_t)l * TH3 * DIM, gwh[l * 2 + 0], gwl[l * 2 + 0], TH3, (size_t)TH3 * 1024);
            k_split_w<<<(TH3 * 1024 / 256), 256, 0, stream>>>(
                w_hh + (size_t)l * TH3 * HID, gwh[l * 2 + 1], gwl[l * 2 + 1], TH3, (size_t)TH3 * 1024);
        }
        k_init_t<<<(NL * NB * HID + 255) / 256, 256, 0, stream>>>(h0, start, hbuf, hth, htl, tok);

        for (int t = 0; t < Tt; ++t) {
            k_prep_x_t<<<NB * DIM / 256, 256, 0, stream>>>(emb, tok, xth, xtl);
            for (int l = 0; l < NL; ++l) {
                const unsigned short* Axh = (l == 0) ? xth : hth;
                const unsigned short* Axl = (l == 0) ? xtl : htl;
                const unsigned short* Ahh = hth + (size_t)l * 65536;
                const unsigned short* Ahl = htl + (size_t)l * 65536;
                k_mm_gru_t<<<dim3(TH3 / 128, GKC, 2), 256, 0, stream>>>(
                    Axh, Axl, Ahh, Ahl,
                    gwh[l * 2 + 0], gwl[l * 2 + 0], gwh[l * 2 + 1], gwl[l * 2 + 1], gpart);
                k_gate_t<<<NB * HID / 256, 256, 0, stream>>>(
                    gpart, b_ih + (size_t)l * TH3, b_hh + (size_t)l * TH3,
                    hbuf + (size_t)l * NB * HID, hth + (size_t)l * 65536, htl + (size_t)l * 65536);
            }
            k_mm_proj_t<<<dim3(VPAD / 128, 2), 256, 0, stream>>>(
                hth + 65536, htl + 65536, bpjh, bpjl, gpart);
            k_reduce2<<<dim3(RCH, NB), 256, 0, stream>>>(gpart, b_proj, logits, red, Vt);
            k_final<<<dim3((Vt + 2047) / 2048, NB), 256, 0, stream>>>(
                logits, red, out_logp, out_tok, tok, Vt, VPAD, Tt, t);
        }
    } else {
        // ---- fallback (round-1) path ----
        char* w = (char*)d_ws;
        float* logitsF       = (float*)w;  w += (size_t)NB * Vt * 4;
        unsigned short* a0hi = (unsigned short*)w;  w += (size_t)NB * DIM * 2;
        unsigned short* a0lo = (unsigned short*)w;  w += (size_t)NB * DIM * 2;
        float* hbufF         = (float*)w;  w += (size_t)NL * NB * HID * 4;
        unsigned short* hhi  = (unsigned short*)w;  w += (size_t)NL * NB * HID * 2;
        unsigned short* hlo  = (unsigned short*)w;  w += (size_t)NL * NB * HID * 2;
        float* gpartF        = (float*)w;  w += (size_t)4 * NB * TH3 * 4;
        float* redF          = (float*)w;  w += (size_t)NB * RCH * 16;
        int* tokF            = (int*)w;    w += 256;

        k_init<<<(NL * NB * HID + 255) / 256, 256, 0, stream>>>(h0, start, hbufF, hhi, hlo, tokF);
        for (int t = 0; t < Tt; ++t) {
            k_prep_x<<<NB * DIM / 256, 256, 0, stream>>>(emb, tokF, a0hi, a0lo);
            for (int l = 0; l < NL; ++l) {
                const unsigned short* Axhi = (l == 0) ? a0hi : hhi;
                const unsigned short* Axlo = (l == 0) ? a0lo : hlo;
                const unsigned short* Ahhi = hhi + (size_t)l * NB * HID;
                const unsigned short* Ahlo = hlo + (size_t)l * NB * HID;
                k_mm_gru<<<dim3(TH3 / 64, 2, 2), 256, 0, stream>>>(
                    Axhi, Axlo, Ahhi, Ahlo,
                    w_ih + (size_t)l * TH3 * DIM, w_hh + (size_t)l * TH3 * HID, gpartF);
                k_gate<<<NB * HID / 256, 256, 0, stream>>>(
                    gpartF, b_ih + (size_t)l * TH3, b_hh + (size_t)l * TH3,
                    hbufF + (size_t)l * NB * HID, hhi + (size_t)l * NB * HID,
                    hlo + (size_t)l * NB * HID);
            }
            k_mm_proj<<<dim3((Vt + 63) / 64, 1, 1), 256, 0, stream>>>(
                hhi + (size_t)NB * HID, hlo + (size_t)NB * HID, w_proj, b_proj, logitsF, Vt);
            k_reduce<<<dim3(RCH, NB), 256, 0, stream>>>(logitsF, redF, Vt, Vt);
            k_final<<<dim3((Vt + 2047) / 2048, NB), 256, 0, stream>>>(
                logitsF, redF, out_logp, out_tok, tokF, Vt, Vt, Tt, t);
        }
    }
}